// Round 3
// baseline (169.022 us; speedup 1.0000x reference)
//
#include <hip/hip_runtime.h>
#include <hip/hip_bf16.h>

// Problem constants (fixed by the reference)
#define NUM_LOC   100000
#define EMB_D     256
#define NCLUST    50
#define NTOK      12800   // B*L = 64*200
#define OUT_D     384     // 256 + 128

// One wave (64 lanes) per token; 4 waves (256 threads) per block.
// grid = NTOK/4 = 3200 blocks.
__global__ __launch_bounds__(256)
void hle_kernel(const int*   __restrict__ loc_ids,        // (B,L) int32
                const float* __restrict__ loc_table,      // (NUM_LOC,256) f32
                const float* __restrict__ cluster_table,  // (50,128) f32
                const float* __restrict__ W_lc,           // (50,NUM_LOC) f32
                const float* __restrict__ b_lc,           // (50,) f32
                float*       __restrict__ out)            // f32 (NTOK,384)
{
    // cluster_table staged in LDS: 50*128*4 = 25.6 KB
    __shared__ float s_ct[NCLUST * 128];

    const int tid = threadIdx.x;

    // --- stage cluster_table into LDS as float4 (1600 float4 / 256 threads) ---
    {
        const float4* src = (const float4*)cluster_table;
        float4* dst = (float4*)s_ct;
        for (int i = tid; i < NCLUST * 32; i += 256)
            dst[i] = src[i];
    }
    __syncthreads();

    const int wave  = tid >> 6;
    const int lane  = tid & 63;
    const int token = blockIdx.x * 4 + wave;   // NTOK divisible by 4; always in range
    const int id    = loc_ids[token];

    // --- issue the fine-row gather early (latency hidden behind softmax) ---
    const float4* fsrc = (const float4*)(loc_table + (size_t)id * EMB_D);
    float4 fine = fsrc[lane];                  // 4 f32 per lane = whole 256-row per wave

    // --- logits: lanes 0..49 gather one W_lc column element + bias ---
    float logit = -INFINITY;
    if (lane < NCLUST)
        logit = W_lc[(size_t)lane * NUM_LOC + id] + b_lc[lane];

    // wave-wide max reduction (width 64)
    float m = logit;
    #pragma unroll
    for (int off = 32; off > 0; off >>= 1)
        m = fmaxf(m, __shfl_xor(m, off, 64));

    float e = (lane < NCLUST) ? __expf(logit - m) : 0.0f;

    float s = e;
    #pragma unroll
    for (int off = 32; off > 0; off >>= 1)
        s += __shfl_xor(s, off, 64);

    const float w = e / s;                     // softmax weight, lane c holds w[c]

    // --- coarse: coarse[d] = sum_c w[c] * ct[c][d]; lane handles d=2*lane, 2*lane+1 ---
    float acc0 = 0.0f, acc1 = 0.0f;
    const float2* ct2 = (const float2*)s_ct;
    #pragma unroll
    for (int c = 0; c < NCLUST; ++c) {
        float wc = __shfl(w, c, 64);           // readlane broadcast
        float2 v = ct2[c * 64 + lane];         // ds_read_b64, 2-way bank mode (free)
        acc0 = fmaf(wc, v.x, acc0);
        acc1 = fmaf(wc, v.y, acc1);
    }

    // --- write output row: [fine(256) | coarse(128)] as f32 ---
    float* orow = out + (size_t)token * OUT_D;

    ((float4*)orow)[lane] = fine;              // bytes 0..1023, coalesced

    float2 cw = make_float2(acc0, acc1);
    ((float2*)(orow + EMB_D))[lane] = cw;      // bytes 1024..1535, coalesced
}

extern "C" void kernel_launch(void* const* d_in, const int* in_sizes, int n_in,
                              void* d_out, int out_size, void* d_ws, size_t ws_size,
                              hipStream_t stream) {
    const int*   loc_ids       = (const int*)d_in[0];
    const float* loc_table     = (const float*)d_in[1];
    const float* cluster_table = (const float*)d_in[2];
    const float* W_lc          = (const float*)d_in[3];
    const float* b_lc          = (const float*)d_in[4];
    float*       out           = (float*)d_out;

    hle_kernel<<<NTOK / 4, 256, 0, stream>>>(loc_ids, loc_table, cluster_table,
                                             W_lc, b_lc, out);
}